// Round 11
// baseline (1279.326 us; speedup 1.0000x reference)
//
#include <hip/hip_runtime.h>
#include <stdint.h>

typedef __attribute__((ext_vector_type(8))) _Float16 half8v;
typedef __attribute__((ext_vector_type(2))) _Float16 half2v;
typedef __attribute__((ext_vector_type(4))) float floatx4;

union H8 { uint4 u; half8v v; half2v h[4]; _Float16 e[8]; };
union H4 { uint2 u; half2v h[2]; _Float16 e[4]; };

__device__ __forceinline__ float bf2f(unsigned int u) {
  union { unsigned int i; float f; } x;
  x.i = u << 16;
  return x.f;
}

#if __has_builtin(__builtin_amdgcn_sdot4)
__device__ __forceinline__ int dot4i(int a, int b, int c) {
  return __builtin_amdgcn_sdot4(a, b, c, false);
}
#else
__device__ __forceinline__ int dot4i(int a, int b, int c) {
  #pragma unroll
  for (int i = 0; i < 4; i++)
    c += (int)(signed char)(a >> (8 * i)) * (int)(signed char)(b >> (8 * i));
  return c;
}
#endif

#if __has_builtin(__builtin_amdgcn_readlane)
__device__ __forceinline__ int rl(int v, int l) { return __builtin_amdgcn_readlane(v, l); }
#else
__device__ __forceinline__ int rl(int v, int l) { return __shfl(v, l, 64); }
#endif
__device__ __forceinline__ float rlf(float v, int l) {
  union { float f; int i; } x; x.f = v;
  x.i = rl(x.i, l);
  return x.f;
}

__device__ __forceinline__ float wave_sum(float v) {
  #pragma unroll
  for (int m = 32; m > 0; m >>= 1) v += __shfl_xor(v, m, 64);
  return v;
}

__device__ __forceinline__ float wave_max(float v) {
  #pragma unroll
  for (int m = 32; m > 0; m >>= 1) v = fmaxf(v, __shfl_xor(v, m, 64));
  return v;
}

__device__ __forceinline__ unsigned short f2bf(float f) {
  union { float f; unsigned int u; } x; x.f = f;
  unsigned int r = x.u + 0x7fffu + ((x.u >> 16) & 1u);
  return (unsigned short)(r >> 16);
}

// -------- dtype detection: flags[0]=edges int64, flags[1]=floats fp32 --------

__global__ void detect_kernel(const int* __restrict__ ei, const unsigned int* __restrict__ w1,
                              int* __restrict__ flags, int E) {
  __shared__ int nz, sane;
  if (threadIdx.x == 0) { nz = 0; sane = 0; }
  __syncthreads();
  for (int i = threadIdx.x; i < 2048; i += blockDim.x) {
    if (i < E && ei[2 * i + 1] != 0) atomicAdd(&nz, 1);
    union { unsigned int u; float f; } c; c.u = w1[i];
    float af = fabsf(c.f);
    if (c.f == c.f && af > 1e-10f && af < 1e10f) atomicAdd(&sane, 1);
  }
  __syncthreads();
  if (threadIdx.x == 0) {
    flags[0] = (nz == 0) ? 1 : 0;
    flags[1] = (sane > 1024) ? 1 : 0;
  }
}

// ---------------- CSR builds ----------------

__global__ void count_kernel(const int* __restrict__ ei, const int* __restrict__ flags,
                             int* __restrict__ cnt, int E, int N) {
  int e = blockIdx.x * blockDim.x + threadIdx.x;
  if (e >= E) return;
  int d = flags[0] ? ei[2 * (E + e)] : ei[E + e];
  d = ((unsigned)d < (unsigned)N) ? d : 0;
  atomicAdd(&cnt[d], 1);
}

__global__ void countS_kernel(const int* __restrict__ srcP, int* __restrict__ cnt, int E) {
  int e = blockIdx.x * blockDim.x + threadIdx.x;
  if (e < E) atomicAdd(&cnt[srcP[e]], 1);
}

__global__ void scan1_kernel(const int* __restrict__ cnt, int* __restrict__ off,
                             int* __restrict__ bsum, int n) {
  __shared__ int buf[1024];
  int t = threadIdx.x;
  int i = blockIdx.x * 1024 + t;
  int v = (i < n) ? cnt[i] : 0;
  buf[t] = v;
  __syncthreads();
  for (int o = 1; o < 1024; o <<= 1) {
    int a = (t >= o) ? buf[t - o] : 0;
    __syncthreads();
    buf[t] += a;
    __syncthreads();
  }
  if (i < n) off[i + 1] = buf[t];
  if (t == 1023) bsum[blockIdx.x] = buf[1023];
}

__global__ void scan2_kernel(int* __restrict__ bsum, int nb) {
  __shared__ int buf[1024];
  int t = threadIdx.x;
  int v = (t < nb) ? bsum[t] : 0;
  buf[t] = v;
  __syncthreads();
  for (int o = 1; o < 1024; o <<= 1) {
    int a = (t >= o) ? buf[t - o] : 0;
    __syncthreads();
    buf[t] += a;
    __syncthreads();
  }
  if (t < nb) bsum[t] = buf[t];
}

// finalize off and seed cur (= final off) in one pass
__global__ void scan3_kernel(int* __restrict__ off, int* __restrict__ cur,
                             const int* __restrict__ bsum, int n) {
  int i = blockIdx.x * blockDim.x + threadIdx.x;
  if (i == 0) { off[0] = 0; cur[0] = 0; }
  if (i < n) {
    int b = i >> 10;
    int v = off[i + 1] + ((b > 0) ? bsum[b - 1] : 0);
    off[i + 1] = v;
    if (i + 1 < n) cur[i + 1] = v;
  }
}

__global__ void fill_kernel(const int* __restrict__ ei, const int* __restrict__ flags,
                            int* __restrict__ cur, int* __restrict__ srcP,
                            int* __restrict__ dstP, int E, int N) {
  int e = blockIdx.x * blockDim.x + threadIdx.x;
  if (e >= E) return;
  int s, d;
  if (flags[0]) { s = ei[2 * e]; d = ei[2 * (E + e)]; }
  else          { s = ei[e];     d = ei[E + e]; }
  s = ((unsigned)s < (unsigned)N) ? s : 0;
  d = ((unsigned)d < (unsigned)N) ? d : 0;
  int pos = atomicAdd(&cur[d], 1);
  srcP[pos] = s;
  dstP[pos] = d;
}

__global__ void fillS_kernel(const int* __restrict__ srcP, int* __restrict__ cur,
                             int* __restrict__ eidS, int E) {
  int j = blockIdx.x * blockDim.x + threadIdx.x;
  if (j >= E) return;
  int pos = atomicAdd(&cur[srcP[j]], 1);
  eidS[pos] = j;
}

// -- layer-1 convert+norm: fp32/bf16 x -> f16 rows + int8 rows + invq --------

__global__ __launch_bounds__(256) void convert_norm_kernel(
    const float* __restrict__ xf, const unsigned short* __restrict__ xb,
    const int* __restrict__ flags, _Float16* __restrict__ xo,
    unsigned char* __restrict__ xq, float* __restrict__ invq, int n) {
  int row = blockIdx.x * 4 + (threadIdx.x >> 6);
  int lane = threadIdx.x & 63;
  if (row >= n) return;
  float ss = 0.f, mx = 0.f;
  float vals[8];
  H8 o;
  if (flags[1]) {
    const float4* vp = reinterpret_cast<const float4*>(xf + (size_t)row * 512) + lane * 2;
    float4 a = vp[0], b = vp[1];
    vals[0] = a.x; vals[1] = a.y; vals[2] = a.z; vals[3] = a.w;
    vals[4] = b.x; vals[5] = b.y; vals[6] = b.z; vals[7] = b.w;
  } else {
    uint4 v = *(reinterpret_cast<const uint4*>(xb + (size_t)row * 512) + lane);
    unsigned int a[4] = {v.x, v.y, v.z, v.w};
    #pragma unroll
    for (int i = 0; i < 4; i++) {
      vals[2 * i] = bf2f(a[i] & 0xffffu);
      vals[2 * i + 1] = bf2f(a[i] >> 16);
    }
  }
  #pragma unroll
  for (int i = 0; i < 8; i++) {
    ss += vals[i] * vals[i];
    mx = fmaxf(mx, fabsf(vals[i]));
    o.v[i] = (_Float16)vals[i];
  }
  *(reinterpret_cast<uint4*>(xo + (size_t)row * 512) + lane) = o.u;
  ss = wave_sum(ss);
  mx = wave_max(mx);
  float scale = (mx > 0.f) ? 127.0f / mx : 0.f;
  uint2 qo;
  unsigned int q0 = 0, q1 = 0;
  #pragma unroll
  for (int i = 0; i < 4; i++) {
    int q = (int)rintf(vals[i] * scale);
    q0 |= ((unsigned int)(q & 0xff)) << (8 * i);
  }
  #pragma unroll
  for (int i = 0; i < 4; i++) {
    int q = (int)rintf(vals[4 + i] * scale);
    q1 |= ((unsigned int)(q & 0xff)) << (8 * i);
  }
  qo.x = q0; qo.y = q1;
  *(reinterpret_cast<uint2*>(xq + (size_t)row * 512) + lane) = qo;
  if (lane == 0)
    invq[row] = (mx > 0.f && ss > 0.f) ? (mx / 127.0f) * rsqrtf(ss) : 0.f;
}

// fallback norm over raw x
__global__ __launch_bounds__(256) void norm8_kernel(const unsigned short* __restrict__ hb,
                                                    const float* __restrict__ hf,
                                                    const int* __restrict__ flags,
                                                    float* __restrict__ invn, int n) {
  int wid = blockIdx.x * 4 + (threadIdx.x >> 6);
  int lane = threadIdx.x & 63;
  if (wid >= n) return;
  float s = 0.f;
  if (flags[1]) {
    const float4* vp = reinterpret_cast<const float4*>(hf + (size_t)wid * 512) + lane * 2;
    float4 a = vp[0], b = vp[1];
    s = a.x*a.x + a.y*a.y + a.z*a.z + a.w*a.w + b.x*b.x + b.y*b.y + b.z*b.z + b.w*b.w;
  } else {
    uint4 v = *(reinterpret_cast<const uint4*>(hb + (size_t)wid * 512) + lane);
    unsigned int a[4] = {v.x, v.y, v.z, v.w};
    #pragma unroll
    for (int i = 0; i < 4; i++) {
      float lo = bf2f(a[i] & 0xffffu), hi = bf2f(a[i] >> 16);
      s += lo * lo + hi * hi;
    }
  }
  s = wave_sum(s);
  if (lane == 0) invn[wid] = (s == 0.f) ? 1.0f : rsqrtf(s);
}

// --- int8 cosine sim: 16-lane groups, 4 edges/wave x 2 batches, sdot4 ------
// ATOMIC=false: pure w[j] writer (rowsum/degcnt computed later via src-CSR).

template<int RB, bool ATOMIC>
__global__ __launch_bounds__(256) void simq2_kernel(const unsigned char* __restrict__ q,
                                                    const int* __restrict__ srcP,
                                                    const int* __restrict__ dstP,
                                                    const float* __restrict__ invq,
                                                    float* __restrict__ w,
                                                    float* __restrict__ rowsum,
                                                    float* __restrict__ degcnt,
                                                    int E, int chunk) {
  int nb = (blockIdx.x & 7) * chunk + (blockIdx.x >> 3);
  int lane = threadIdx.x & 63;
  int l = lane & 15, g = lane >> 4;
  int j0 = (nb * 4 + (threadIdx.x >> 6)) * 8;
  if (j0 >= E) return;
  int sj[2], tj[2];
  bool val[2];
  #pragma unroll
  for (int b = 0; b < 2; b++) {
    int j = j0 + b * 4 + g;
    val[b] = j < E;
    int jj = val[b] ? j : 0;
    sj[b] = srcP[jj];
    tj[b] = dstP[jj];
  }
  int acc[2];
  if constexpr (RB == 512) {
    uint4 sa[2][2], ta[2][2];
    #pragma unroll
    for (int b = 0; b < 2; b++) {
      const unsigned char* sp = q + (size_t)sj[b] * 512 + l * 16;
      const unsigned char* tp = q + (size_t)tj[b] * 512 + l * 16;
      sa[b][0] = *reinterpret_cast<const uint4*>(sp);
      sa[b][1] = *reinterpret_cast<const uint4*>(sp + 256);
      ta[b][0] = *reinterpret_cast<const uint4*>(tp);
      ta[b][1] = *reinterpret_cast<const uint4*>(tp + 256);
    }
    #pragma unroll
    for (int b = 0; b < 2; b++) {
      int a = 0;
      a = dot4i((int)sa[b][0].x, (int)ta[b][0].x, a);
      a = dot4i((int)sa[b][0].y, (int)ta[b][0].y, a);
      a = dot4i((int)sa[b][0].z, (int)ta[b][0].z, a);
      a = dot4i((int)sa[b][0].w, (int)ta[b][0].w, a);
      a = dot4i((int)sa[b][1].x, (int)ta[b][1].x, a);
      a = dot4i((int)sa[b][1].y, (int)ta[b][1].y, a);
      a = dot4i((int)sa[b][1].z, (int)ta[b][1].z, a);
      a = dot4i((int)sa[b][1].w, (int)ta[b][1].w, a);
      acc[b] = a;
    }
  } else if constexpr (RB == 256) {
    uint4 sa[2], ta[2];
    #pragma unroll
    for (int b = 0; b < 2; b++) {
      sa[b] = *reinterpret_cast<const uint4*>(q + (size_t)sj[b] * 256 + l * 16);
      ta[b] = *reinterpret_cast<const uint4*>(q + (size_t)tj[b] * 256 + l * 16);
    }
    #pragma unroll
    for (int b = 0; b < 2; b++) {
      int a = 0;
      a = dot4i((int)sa[b].x, (int)ta[b].x, a);
      a = dot4i((int)sa[b].y, (int)ta[b].y, a);
      a = dot4i((int)sa[b].z, (int)ta[b].z, a);
      a = dot4i((int)sa[b].w, (int)ta[b].w, a);
      acc[b] = a;
    }
  } else {  // RB == 64
    unsigned int sa[2], ta[2];
    #pragma unroll
    for (int b = 0; b < 2; b++) {
      sa[b] = *reinterpret_cast<const unsigned int*>(q + (size_t)sj[b] * 64 + l * 4);
      ta[b] = *reinterpret_cast<const unsigned int*>(q + (size_t)tj[b] * 64 + l * 4);
    }
    #pragma unroll
    for (int b = 0; b < 2; b++) acc[b] = dot4i((int)sa[b], (int)ta[b], 0);
  }
  #pragma unroll
  for (int m = 1; m < 16; m <<= 1) {
    acc[0] += __shfl_xor(acc[0], m, 64);
    acc[1] += __shfl_xor(acc[1], m, 64);
  }
  if (l == 0) {
    #pragma unroll
    for (int b = 0; b < 2; b++) {
      if (val[b]) {
        int j = j0 + b * 4 + g;
        float simv = (float)acc[b] * invq[sj[b]] * invq[tj[b]];
        float wv = (sj[b] != tj[b] && simv > 0.f) ? simv : 0.f;
        w[j] = wv;
        if constexpr (ATOMIC) {
          if (wv > 0.f) {
            atomicAdd(&rowsum[sj[b]], wv);
            atomicAdd(&degcnt[sj[b]], 1.0f);
          }
        }
      }
    }
  }
}

// fallback layer-1 sim on raw x (atomic)
__global__ __launch_bounds__(256) void simf_kernel(const unsigned short* __restrict__ hb,
                                                   const float* __restrict__ hf,
                                                   const int* __restrict__ flags,
                                                   const int* __restrict__ srcP,
                                                   const int* __restrict__ dstP,
                                                   const float* __restrict__ invn,
                                                   float* __restrict__ w,
                                                   float* __restrict__ rowsum,
                                                   float* __restrict__ degcnt, int E) {
  int j = blockIdx.x * 4 + (threadIdx.x >> 6);
  int lane = threadIdx.x & 63;
  if (j >= E) return;
  int s = srcP[j], t = dstP[j];
  float acc = 0.f;
  if (flags[1]) {
    const float4* ap = reinterpret_cast<const float4*>(hf + (size_t)s * 512) + lane * 2;
    const float4* bp = reinterpret_cast<const float4*>(hf + (size_t)t * 512) + lane * 2;
    float4 a0 = ap[0], a1 = ap[1], b0 = bp[0], b1 = bp[1];
    acc = a0.x*b0.x + a0.y*b0.y + a0.z*b0.z + a0.w*b0.w
        + a1.x*b1.x + a1.y*b1.y + a1.z*b1.z + a1.w*b1.w;
  } else {
    uint4 a = *(reinterpret_cast<const uint4*>(hb + (size_t)s * 512) + lane);
    uint4 b = *(reinterpret_cast<const uint4*>(hb + (size_t)t * 512) + lane);
    unsigned int av[4] = {a.x, a.y, a.z, a.w};
    unsigned int bv[4] = {b.x, b.y, b.z, b.w};
    #pragma unroll
    for (int i = 0; i < 4; i++)
      acc += bf2f(av[i] & 0xffffu) * bf2f(bv[i] & 0xffffu)
           + bf2f(av[i] >> 16) * bf2f(bv[i] >> 16);
  }
  acc = wave_sum(acc);
  if (lane == 0) {
    float simv = acc * invn[s] * invn[t];
    float wv = (s != t && simv > 0.f) ? simv : 0.f;
    w[j] = wv;
    if (wv > 0.f) {
      atomicAdd(&rowsum[s], wv);
      atomicAdd(&degcnt[s], 1.0f);
    }
  }
}

// ------ rowsum/degcnt via src-CSR (no atomics), wave-per-node ------

__global__ __launch_bounds__(256) void rowsumS_kernel(
    const float* __restrict__ w, const int* __restrict__ eidS,
    const int* __restrict__ offS, float* __restrict__ rowsum,
    float* __restrict__ degcnt, int n) {
  int i = blockIdx.x * 4 + (threadIdx.x >> 6);
  if (i >= n) return;
  int lane = threadIdx.x & 63;
  int e0 = offS[i], e1 = offS[i + 1];
  float s = 0.f, c = 0.f;
  for (int j = e0 + lane; j < e1; j += 64) {
    float wv = w[eidS[j]];
    if (wv > 0.f) { s += wv; c += 1.f; }
  }
  s = wave_sum(s);
  c = wave_sum(c);
  if (lane == 0) { rowsum[i] = s; degcnt[i] = c; }
}

// ------ fused deg pass (dst-CSR, wave-per-node) ------
// w -> ew = exp(w / rowsum[src]); dinv = rsqrt(sw + sum(ew)); sw out.

__global__ __launch_bounds__(256) void deg_kernel(
    float* __restrict__ w, const int* __restrict__ srcP, const int* __restrict__ off,
    const float* __restrict__ rowsum, const float* __restrict__ degcnt,
    float* __restrict__ sw, float* __restrict__ dinv, int n) {
  int i = blockIdx.x * 4 + (threadIdx.x >> 6);
  if (i >= n) return;
  int lane = threadIdx.x & 63;
  int e0 = off[i], e1 = off[i + 1];
  float sum = 0.f;
  for (int j = e0 + lane; j < e1; j += 64) {
    float wv = w[j];
    if (wv > 0.f) {
      float ew = expf(wv / rowsum[srcP[j]]);
      w[j] = ew;
      sum += ew;
    }
  }
  sum = wave_sum(sum);
  float swi = expf(1.0f / (degcnt[i] + 1.0f));
  if (lane == 0) {
    sw[i] = swi;
    dinv[i] = rsqrtf(swi + sum);
  }
}

// ---------------- GEMM (f16 MFMA) ----------------

__global__ void transpose_kernel(const unsigned short* __restrict__ Wb,
                                 const float* __restrict__ Wf,
                                 const int* __restrict__ flags,
                                 _Float16* __restrict__ WT,
                                 int K, int Nc, int Npad) {
  int idx = blockIdx.x * blockDim.x + threadIdx.x;
  if (idx >= Npad * K) return;
  int nn = idx / K, k = idx - nn * K;
  _Float16 v = (_Float16)0.f;
  if (nn < Nc) {
    if (flags[1]) v = (_Float16)Wf[(size_t)k * Nc + nn];
    else          v = (_Float16)bf2f((unsigned int)Wb[(size_t)k * Nc + nn]);
  }
  WT[idx] = v;
}

// layer 1: k-blocked layout WTb[kk][nn][kidx], chunk = 256n x 32k = 8192
__global__ void transpose1_kernel(const unsigned short* __restrict__ Wb,
                                  const float* __restrict__ Wf,
                                  const int* __restrict__ flags,
                                  _Float16* __restrict__ WTb) {
  int idx = blockIdx.x * blockDim.x + threadIdx.x;
  if (idx >= 512 * 256) return;
  int kk = idx >> 13;
  int rem = idx & 8191;
  int nn = rem >> 5;
  int kidx = rem & 31;
  int k = kk * 32 + kidx;
  _Float16 v;
  if (flags[1]) v = (_Float16)Wf[k * 256 + nn];
  else          v = (_Float16)bf2f((unsigned int)Wb[k * 256 + nn]);
  WTb[idx] = v;
}

// layer-1 GEMM with LDS-staged B
__global__ __launch_bounds__(256) void gemm1_lds_kernel(
    const _Float16* __restrict__ Ah, const float* __restrict__ Af,
    const unsigned short* __restrict__ Abf, const int* __restrict__ flags,
    int useflags, const _Float16* __restrict__ BTb, _Float16* __restrict__ C,
    int M) {
  constexpr int NT = 16, KSTEPS = 16, K = 512, LS = 40;
  __shared__ _Float16 bs[256 * LS];
  int t = threadIdx.x;
  int wid = t >> 6, lane = t & 63;
  int mt = blockIdx.x * 4 + wid;
  bool act = (mt * 16 < M);
  int r = lane & 15, quad = lane >> 4;
  int m0 = mt * 16;
  int mode = useflags ? (flags[1] ? 1 : 2) : 0;
  floatx4 acc[NT];
  #pragma unroll
  for (int nt = 0; nt < NT; nt++) acc[nt] = floatx4{0.f, 0.f, 0.f, 0.f};
  int arow = act ? (m0 + r) : 0;
  const uint4* ap = reinterpret_cast<const uint4*>(Ah + (size_t)arow * K);
  const float* af = Af + (size_t)arow * K + quad * 8;
  const unsigned short* ab = Abf + (size_t)arow * K + quad * 8;
  for (int kk = 0; kk < KSTEPS; kk++) {
    __syncthreads();
    {
      const uint4* bsrc = reinterpret_cast<const uint4*>(BTb + kk * 8192) + t * 4;
      uint4 b0 = bsrc[0], b1 = bsrc[1], b2 = bsrc[2], b3 = bsrc[3];
      uint4* bdst = reinterpret_cast<uint4*>(bs + t * LS);
      bdst[0] = b0; bdst[1] = b1; bdst[2] = b2; bdst[3] = b3;
    }
    __syncthreads();
    if (act) {
      H8 a;
      if (mode == 1) {
        float4 x0 = *reinterpret_cast<const float4*>(af + kk * 32);
        float4 x1 = *reinterpret_cast<const float4*>(af + kk * 32 + 4);
        a.v[0] = (_Float16)x0.x; a.v[1] = (_Float16)x0.y;
        a.v[2] = (_Float16)x0.z; a.v[3] = (_Float16)x0.w;
        a.v[4] = (_Float16)x1.x; a.v[5] = (_Float16)x1.y;
        a.v[6] = (_Float16)x1.z; a.v[7] = (_Float16)x1.w;
      } else if (mode == 2) {
        uint4 u = *reinterpret_cast<const uint4*>(ab + kk * 32);
        unsigned int uu[4] = {u.x, u.y, u.z, u.w};
        #pragma unroll
        for (int i = 0; i < 4; i++) {
          a.v[2 * i] = (_Float16)bf2f(uu[i] & 0xffffu);
          a.v[2 * i + 1] = (_Float16)bf2f(uu[i] >> 16);
        }
      } else {
        a.u = ap[(kk << 2) + quad];
      }
      #pragma unroll
      for (int nt = 0; nt < NT; nt++) {
        H8 b;
        b.u = *reinterpret_cast<const uint4*>(bs + (nt * 16 + r) * LS + quad * 8);
        acc[nt] = __builtin_amdgcn_mfma_f32_16x16x32_f16(a.v, b.v, acc[nt], 0, 0, 0);
      }
    }
  }
  if (act) {
    #pragma unroll
    for (int nt = 0; nt < NT; nt++) {
      #pragma unroll
      for (int i = 0; i < 4; i++)
        C[(size_t)(m0 + quad * 4 + i) * 256 + nt * 16 + r] = (_Float16)acc[nt][i];
    }
  }
}

// layers 2/3 wide GEMM
template<int NT, int KSTEPS>
__global__ __launch_bounds__(256) void gemmw_kernel(const _Float16* __restrict__ Ah,
                                                    const _Float16* __restrict__ BT,
                                                    _Float16* __restrict__ C,
                                                    int M, int Npad) {
  constexpr int K = KSTEPS * 32;
  int mt = blockIdx.x * 4 + (threadIdx.x >> 6);
  if (mt * 16 >= M) return;
  int lane = threadIdx.x & 63;
  int r = lane & 15, quad = lane >> 4;
  int m0 = mt * 16;
  floatx4 acc[NT];
  #pragma unroll
  for (int nt = 0; nt < NT; nt++) acc[nt] = floatx4{0.f, 0.f, 0.f, 0.f};
  const uint4* ap = reinterpret_cast<const uint4*>(Ah + (size_t)(m0 + r) * K);
  for (int kk = 0; kk < KSTEPS; kk++) {
    H8 a;
    a.u = ap[(kk << 2) + quad];
    #pragma unroll
    for (int nt = 0; nt < NT; nt++) {
      H8 b;
      b.u = *reinterpret_cast<const uint4*>(BT + (size_t)(nt * 16 + r) * K + kk * 32 + quad * 8);
      acc[nt] = __builtin_amdgcn_mfma_f32_16x16x32_f16(a.v, b.v, acc[nt], 0, 0, 0);
    }
  }
  #pragma unroll
  for (int nt = 0; nt < NT; nt++) {
    #pragma unroll
    for (int i = 0; i < 4; i++)
      C[(size_t)(m0 + quad * 4 + i) * Npad + nt * 16 + r] = (_Float16)acc[nt][i];
  }
}

// ------- aggregation: wave-per-node, scalar broadcast, no LDS/barriers -------

template<int NC, int STRIDE, int VEC, bool DOQ>
__global__ __launch_bounds__(256) void aggw_relu_kernel(
    const _Float16* __restrict__ hp, const float* __restrict__ ew,
    const int* __restrict__ srcP, const int* __restrict__ off,
    const float* __restrict__ dinv, const float* __restrict__ sw,
    const unsigned short* __restrict__ biasb, const float* __restrict__ biasf,
    const int* __restrict__ flags, _Float16* __restrict__ out,
    unsigned char* __restrict__ qout, float* __restrict__ invn, int n) {
  constexpr int ACT = NC / VEC;
  int i = blockIdx.x * 4 + (threadIdx.x >> 6);
  if (i >= n) return;
  int lane = threadIdx.x & 63;
  float di = dinv[i];
  float sii = sw[i] * di * di;
  float acc[VEC];
  #pragma unroll
  for (int v = 0; v < VEC; v++) acc[v] = 0.f;
  if (lane < ACT) {
    if constexpr (VEC == 4) {
      H4 hv;
      hv.u = *reinterpret_cast<const uint2*>(hp + (size_t)i * STRIDE + lane * 4);
      #pragma unroll
      for (int v = 0; v < 4; v++) acc[v] = sii * (float)hv.e[v];
    } else {
      acc[0] = sii * (float)hp[(size_t)i * STRIDE + lane];
    }
  }
  int e0 = off[i], e1 = off[i + 1];
  for (int base = e0; base < e1; base += 64) {
    int j = base + lane;
    int sreg = 0;
    float creg = 0.f;
    if (j < e1) {
      sreg = srcP[j];
      float e = ew[j];
      if (e != 0.f) creg = e * dinv[sreg] * di;
    }
    int m = min(64, e1 - base);
    for (int k = 0; k < m; k++) {
      float cfk = rlf(creg, k);
      if (cfk != 0.f) {
        int sk = rl(sreg, k);
        if (lane < ACT) {
          if constexpr (VEC == 4) {
            H4 hv;
            hv.u = *reinterpret_cast<const uint2*>(hp + (size_t)sk * STRIDE + lane * 4);
            #pragma unroll
            for (int v = 0; v < 4; v++) acc[v] += cfk * (float)hv.e[v];
          } else {
            acc[0] += cfk * (float)hp[(size_t)sk * STRIDE + lane];
          }
        }
      }
    }
  }
  float nrm = 0.f, lmax = 0.f;
  float xv[VEC];
  if (lane < ACT) {
    if constexpr (VEC == 4) {
      H4 ov;
      #pragma unroll
      for (int v = 0; v < 4; v++) {
        int c = lane * 4 + v;
        float bb = flags[1] ? biasf[c] : bf2f((unsigned int)biasb[c]);
        float x = acc[v] + bb;
        x = x > 0.f ? x : 0.f;
        xv[v] = x;
        ov.e[v] = (_Float16)x;
        nrm += x * x;
        lmax = fmaxf(lmax, x);
      }
      *reinterpret_cast<uint2*>(out + (size_t)i * NC + lane * 4) = ov.u;
    } else {
      float bb = flags[1] ? biasf[lane] : bf2f((unsigned int)biasb[lane]);
      float x = acc[0] + bb;
      x = x > 0.f ? x : 0.f;
      xv[0] = x;
      out[(size_t)i * NC + lane] = (_Float16)x;
      nrm = x * x;
      lmax = x;
    }
  }
  nrm = wave_sum(nrm);
  if constexpr (DOQ) {
    float mx = wave_max(lmax);
    float scale = (mx > 0.f) ? 127.0f / mx : 0.f;
    if (lane < ACT) {
      if constexpr (VEC == 4) {
        unsigned int qw = 0;
        #pragma unroll
        for (int v = 0; v < 4; v++) {
          int qq = (int)(xv[v] * scale + 0.5f);
          qw |= ((unsigned int)(qq & 0xff)) << (8 * v);
        }
        *reinterpret_cast<unsigned int*>(qout + (size_t)i * NC + lane * 4) = qw;
      } else {
        qout[(size_t)i * NC + lane] = (unsigned char)(int)(xv[0] * scale + 0.5f);
      }
    }
    if (lane == 0)
      invn[i] = (mx > 0.f && nrm > 0.f) ? (mx / 127.0f) * rsqrtf(nrm) : 0.f;
  } else {
    if (lane == 0) invn[i] = (nrm == 0.f) ? 1.0f : rsqrtf(nrm);
  }
}

__global__ __launch_bounds__(256) void aggw_lsm_kernel(
    const _Float16* __restrict__ hp, const float* __restrict__ ew,
    const int* __restrict__ srcP, const int* __restrict__ off,
    const float* __restrict__ dinv, const float* __restrict__ sw,
    const unsigned short* __restrict__ biasb, const float* __restrict__ biasf,
    const int* __restrict__ flags, void* __restrict__ outv, int n) {
  constexpr int NC = 40, STRIDE = 48;
  int i = blockIdx.x * 4 + (threadIdx.x >> 6);
  if (i >= n) return;
  int lane = threadIdx.x & 63;
  float di = dinv[i];
  float acc = 0.f;
  if (lane < NC) acc = sw[i] * di * di * (float)hp[(size_t)i * STRIDE + lane];
  int e0 = off[i], e1 = off[i + 1];
  for (int base = e0; base < e1; base += 64) {
    int j = base + lane;
    int sreg = 0;
    float creg = 0.f;
    if (j < e1) {
      sreg = srcP[j];
      float e = ew[j];
      if (e != 0.f) creg = e * dinv[sreg] * di;
    }
    int m = min(64, e1 - base);
    for (int k = 0; k < m; k++) {
      float cfk = rlf(creg, k);
      if (cfk != 0.f) {
        int sk = rl(sreg, k);
        if (lane < NC) acc += cfk * (float)hp[(size_t)sk * STRIDE + lane];
      }
    }
  }
  int f32 = flags[1];
  float bb = 0.f;
  if (lane < NC) bb = f32 ? biasf[lane] : bf2f((unsigned int)biasb[lane]);
  float v = (lane < NC) ? acc + bb : -3.0e38f;
  float vm = wave_max(v);
  float ex = (lane < NC) ? expf(v - vm) : 0.f;
  float se = wave_sum(ex);
  float ls = logf(se);
  if (lane < NC) {
    float r = v - vm - ls;
    if (f32) ((float*)outv)[(size_t)i * NC + lane] = r;
    else ((unsigned short*)outv)[(size_t)i * NC + lane] = f2bf(r);
  }
}

// ---------------- host ----------------

extern "C" void kernel_launch(void* const* d_in, const int* in_sizes, int n_in,
                              void* d_out, int out_size, void* d_ws, size_t ws_size,
                              hipStream_t stream) {
  const unsigned short* xb = (const unsigned short*)d_in[0];
  const float* xf          = (const float*)d_in[0];
  const int* ei            = (const int*)d_in[1];

  const int H  = in_sizes[3];            // 256
  const int F  = in_sizes[2] / H;        // 512
  const int D2 = in_sizes[5];            // 64
  const int C  = in_sizes[7];            // 40
  const int N  = in_sizes[0] / F;        // 50000
  const int E  = in_sizes[1] / 2;        // 1600000
  const int CP = 48;

  char* p = (char*)d_ws;
  auto alloc = [&](size_t bytes) -> char* {
    char* r = p;
    p += (bytes + 255) & ~(size_t)255;
    return r;
  };
  int*   srcP   = (int*)alloc((size_t)E * 4 + 32);
  int*   dstP   = (int*)alloc((size_t)E * 4 + 32);
  float* wbuf   = (float*)alloc((size_t)E * 4);
  int*   off    = (int*)alloc((size_t)(N + 1) * 4);
  int*   cur    = (int*)alloc((size_t)N * 4);
  float* invn   = (float*)alloc((size_t)N * 4);
  float* rowsum = (float*)alloc((size_t)N * 4);
  float* degcnt = (float*)alloc((size_t)N * 4);
  float* sw     = (float*)alloc((size_t)N * 4);
  float* dinv   = (float*)alloc((size_t)N * 4);
  int*   flags  = (int*)alloc(256);
  int*   bsum   = (int*)alloc(4096 * 4);
  _Float16* WT  = (_Float16*)alloc((size_t)256 * 512 * 2);
  _Float16* hp  = (_Float16*)alloc((size_t)N * 256 * 2);
  size_t used = (size_t)(p - (char*)d_ws);
  size_t xh_bytes = (size_t)N * 512 * 2;
  size_t srccsr_bytes = (size_t)E * 4 + (size_t)(N + 1) * 4 + 1024;
  bool big = (used + xh_bytes + srccsr_bytes + 1024) <= ws_size;
  _Float16* xh = big ? (_Float16*)alloc(xh_bytes) : hp;
  int* eidS = big ? (int*)alloc((size_t)E * 4) : nullptr;
  int* offS = big ? (int*)alloc((size_t)(N + 1) * 4) : nullptr;

  unsigned char* xq = (unsigned char*)hp;                         // N*512 B
  _Float16* h1 = (_Float16*)d_in[0];                              // N*512 B (f16)
  unsigned char* h1q = (unsigned char*)d_in[0] + (size_t)N * 512; // N*256 B
  unsigned char* h2q = (unsigned char*)d_in[0] + (size_t)N * 768; // N*64 B
  _Float16* h2 = hp + (size_t)N * 64;
  size_t rd_span = (size_t)((char*)degcnt - (char*)rowsum) + (size_t)N * 4;

  const int TB = 256;
  int nblk = (N + TB - 1) / TB;
  int eblk = (E + TB - 1) / TB;
  int nwav = (N + 3) / 4;
  int ewav = (E + 3) / 4;
  int mt4  = (N / 16 + 3) / 4;
  int nb1024 = (N + 1023) / 1024;
  int sblocks8 = (E + 31) / 32;
  int schunk8 = (sblocks8 + 7) / 8;
  int sgrid8 = schunk8 * 8;

  detect_kernel<<<1, 256, 0, stream>>>(ei, (const unsigned int*)d_in[2], flags, E);

  // dst-CSR: srcP/dstP in dst-sorted order
  hipMemsetAsync(cur, 0, (size_t)N * 4, stream);
  count_kernel<<<eblk, TB, 0, stream>>>(ei, flags, cur, E, N);
  scan1_kernel<<<nb1024, 1024, 0, stream>>>(cur, off, bsum, N);
  scan2_kernel<<<1, 1024, 0, stream>>>(bsum, nb1024);
  scan3_kernel<<<nblk, TB, 0, stream>>>(off, cur, bsum, N);
  fill_kernel<<<eblk, TB, 0, stream>>>(ei, flags, cur, srcP, dstP, E, N);

  // src-CSR: eidS = edge indices grouped by src (cur/bsum reused as scratch)
  if (big) {
    hipMemsetAsync(cur, 0, (size_t)N * 4, stream);
    countS_kernel<<<eblk, TB, 0, stream>>>(srcP, cur, E);
    scan1_kernel<<<nb1024, 1024, 0, stream>>>(cur, offS, bsum, N);
    scan2_kernel<<<1, 1024, 0, stream>>>(bsum, nb1024);
    scan3_kernel<<<nblk, TB, 0, stream>>>(offS, cur, bsum, N);
    fillS_kernel<<<eblk, TB, 0, stream>>>(srcP, cur, eidS, E);
  }

  // ---------- layer 1: x(512) -> h1(256) ----------
  if (big) {
    convert_norm_kernel<<<nwav, TB, 0, stream>>>(xf, xb, flags, xh, xq, invn, N);
    simq2_kernel<512, false><<<sgrid8, TB, 0, stream>>>(xq, srcP, dstP, invn, wbuf, nullptr, nullptr, E, schunk8);
    rowsumS_kernel<<<nwav, TB, 0, stream>>>(wbuf, eidS, offS, rowsum, degcnt, N);
  } else {
    hipMemsetAsync(rowsum, 0, rd_span, stream);
    norm8_kernel<<<nwav, TB, 0, stream>>>(xb, xf, flags, invn, N);
    simf_kernel<<<ewav, TB, 0, stream>>>(xb, xf, flags, srcP, dstP, invn, wbuf, rowsum, degcnt, E);
  }
  deg_kernel<<<nwav, TB, 0, stream>>>(wbuf, srcP, off, rowsum, degcnt, sw, dinv, N);
  transpose1_kernel<<<(512 * 256 + TB - 1) / TB, TB, 0, stream>>>(
      (const unsigned short*)d_in[2], (const float*)d_in[2], flags, WT);
  gemm1_lds_kernel<<<mt4, TB, 0, stream>>>(
      xh, xf, xb, flags, big ? 0 : 1, WT, hp, N);
  aggw_relu_kernel<256, 256, 4, true><<<nwav, TB, 0, stream>>>(
      hp, wbuf, srcP, off, dinv, sw,
      (const unsigned short*)d_in[3], (const float*)d_in[3], flags, h1, h1q, invn, N);

  // ---------- layer 2: h1(256) -> h2(64) ----------
  if (big) {
    simq2_kernel<256, false><<<sgrid8, TB, 0, stream>>>(h1q, srcP, dstP, invn, wbuf, nullptr, nullptr, E, schunk8);
    rowsumS_kernel<<<nwav, TB, 0, stream>>>(wbuf, eidS, offS, rowsum, degcnt, N);
  } else {
    hipMemsetAsync(rowsum, 0, rd_span, stream);
    simq2_kernel<256, true><<<sgrid8, TB, 0, stream>>>(h1q, srcP, dstP, invn, wbuf, rowsum, degcnt, E, schunk8);
  }
  deg_kernel<<<nwav, TB, 0, stream>>>(wbuf, srcP, off, rowsum, degcnt, sw, dinv, N);
  transpose_kernel<<<(D2 * H + TB - 1) / TB, TB, 0, stream>>>(
      (const unsigned short*)d_in[4], (const float*)d_in[4], flags, WT, H, D2, D2);
  gemmw_kernel<4, 8><<<mt4, TB, 0, stream>>>(h1, WT, hp, N, D2);
  aggw_relu_kernel<64, 64, 1, true><<<nwav, TB, 0, stream>>>(
      hp, wbuf, srcP, off, dinv, sw,
      (const unsigned short*)d_in[5], (const float*)d_in[5], flags, h2, h2q, invn, N);

  // ---------- layer 3: h2(64) -> out(40), fused log_softmax ----------
  if (big) {
    simq2_kernel<64, false><<<sgrid8, TB, 0, stream>>>(h2q, srcP, dstP, invn, wbuf, nullptr, nullptr, E, schunk8);
    rowsumS_kernel<<<nwav, TB, 0, stream>>>(wbuf, eidS, offS, rowsum, degcnt, N);
  } else {
    hipMemsetAsync(rowsum, 0, rd_span, stream);
    simq2_kernel<64, true><<<sgrid8, TB, 0, stream>>>(h2q, srcP, dstP, invn, wbuf, rowsum, degcnt, E, schunk8);
  }
  deg_kernel<<<nwav, TB, 0, stream>>>(wbuf, srcP, off, rowsum, degcnt, sw, dinv, N);
  transpose_kernel<<<(CP * D2 + TB - 1) / TB, TB, 0, stream>>>(
      (const unsigned short*)d_in[6], (const float*)d_in[6], flags, WT, D2, C, CP);
  gemmw_kernel<3, 2><<<mt4, TB, 0, stream>>>(h2, WT, hp, N, CP);
  aggw_lsm_kernel<<<nwav, TB, 0, stream>>>(
      hp, wbuf, srcP, off, dinv, sw,
      (const unsigned short*)d_in[7], (const float*)d_in[7], flags, d_out, N);
}

// Round 12
// 1088.195 us; speedup vs baseline: 1.1756x; 1.1756x over previous
//
#include <hip/hip_runtime.h>
#include <stdint.h>

typedef __attribute__((ext_vector_type(8))) _Float16 half8v;
typedef __attribute__((ext_vector_type(2))) _Float16 half2v;
typedef __attribute__((ext_vector_type(4))) float floatx4;

union H8 { uint4 u; half8v v; half2v h[4]; _Float16 e[8]; };
union H4 { uint2 u; half2v h[2]; _Float16 e[4]; };

#define CNT_SCALE 1048576.0   // 2^20: degcnt lives above, rowsum below

__device__ __forceinline__ float bf2f(unsigned int u) {
  union { unsigned int i; float f; } x;
  x.i = u << 16;
  return x.f;
}

#if __has_builtin(__builtin_amdgcn_sdot4)
__device__ __forceinline__ int dot4i(int a, int b, int c) {
  return __builtin_amdgcn_sdot4(a, b, c, false);
}
#else
__device__ __forceinline__ int dot4i(int a, int b, int c) {
  #pragma unroll
  for (int i = 0; i < 4; i++)
    c += (int)(signed char)(a >> (8 * i)) * (int)(signed char)(b >> (8 * i));
  return c;
}
#endif

#if __has_builtin(__builtin_amdgcn_readlane)
__device__ __forceinline__ int rl(int v, int l) { return __builtin_amdgcn_readlane(v, l); }
#else
__device__ __forceinline__ int rl(int v, int l) { return __shfl(v, l, 64); }
#endif
__device__ __forceinline__ float rlf(float v, int l) {
  union { float f; int i; } x; x.f = v;
  x.i = rl(x.i, l);
  return x.f;
}

__device__ __forceinline__ float wave_sum(float v) {
  #pragma unroll
  for (int m = 32; m > 0; m >>= 1) v += __shfl_xor(v, m, 64);
  return v;
}

__device__ __forceinline__ float wave_max(float v) {
  #pragma unroll
  for (int m = 32; m > 0; m >>= 1) v = fmaxf(v, __shfl_xor(v, m, 64));
  return v;
}

__device__ __forceinline__ unsigned short f2bf(float f) {
  union { float f; unsigned int u; } x; x.f = f;
  unsigned int r = x.u + 0x7fffu + ((x.u >> 16) & 1u);
  return (unsigned short)(r >> 16);
}

// -------- dtype detection: flags[0]=edges int64, flags[1]=floats fp32 --------

__global__ void detect_kernel(const int* __restrict__ ei, const unsigned int* __restrict__ w1,
                              int* __restrict__ flags, int E) {
  __shared__ int nz, sane;
  if (threadIdx.x == 0) { nz = 0; sane = 0; }
  __syncthreads();
  for (int i = threadIdx.x; i < 2048; i += blockDim.x) {
    if (i < E && ei[2 * i + 1] != 0) atomicAdd(&nz, 1);
    union { unsigned int u; float f; } c; c.u = w1[i];
    float af = fabsf(c.f);
    if (c.f == c.f && af > 1e-10f && af < 1e10f) atomicAdd(&sane, 1);
  }
  __syncthreads();
  if (threadIdx.x == 0) {
    flags[0] = (nz == 0) ? 1 : 0;
    flags[1] = (sane > 1024) ? 1 : 0;
  }
}

// ---------------- CSR build (by dst), packed (src,dst) ----------------

__global__ void count_kernel(const int* __restrict__ ei, const int* __restrict__ flags,
                             int* __restrict__ cnt, int E, int N) {
  int e = blockIdx.x * blockDim.x + threadIdx.x;
  if (e >= E) return;
  int d = flags[0] ? ei[2 * (E + e)] : ei[E + e];
  d = ((unsigned)d < (unsigned)N) ? d : 0;
  atomicAdd(&cnt[d], 1);
}

__global__ void scan1_kernel(const int* __restrict__ cnt, int* __restrict__ off,
                             int* __restrict__ bsum, int n) {
  __shared__ int buf[1024];
  int t = threadIdx.x;
  int i = blockIdx.x * 1024 + t;
  int v = (i < n) ? cnt[i] : 0;
  buf[t] = v;
  __syncthreads();
  for (int o = 1; o < 1024; o <<= 1) {
    int a = (t >= o) ? buf[t - o] : 0;
    __syncthreads();
    buf[t] += a;
    __syncthreads();
  }
  if (i < n) off[i + 1] = buf[t];
  if (t == 1023) bsum[blockIdx.x] = buf[1023];
}

__global__ void scan2_kernel(int* __restrict__ bsum, int nb) {
  __shared__ int buf[1024];
  int t = threadIdx.x;
  int v = (t < nb) ? bsum[t] : 0;
  buf[t] = v;
  __syncthreads();
  for (int o = 1; o < 1024; o <<= 1) {
    int a = (t >= o) ? buf[t - o] : 0;
    __syncthreads();
    buf[t] += a;
    __syncthreads();
  }
  if (t < nb) bsum[t] = buf[t];
}

__global__ void scan3_kernel(int* __restrict__ off, int* __restrict__ cur,
                             const int* __restrict__ bsum, int n) {
  int i = blockIdx.x * blockDim.x + threadIdx.x;
  if (i == 0) { off[0] = 0; cur[0] = 0; }
  if (i < n) {
    int b = i >> 10;
    int v = off[i + 1] + ((b > 0) ? bsum[b - 1] : 0);
    off[i + 1] = v;
    if (i + 1 < n) cur[i + 1] = v;
  }
}

__global__ void fill_kernel(const int* __restrict__ ei, const int* __restrict__ flags,
                            int* __restrict__ cur, int2* __restrict__ edgeSD,
                            int E, int N) {
  int e = blockIdx.x * blockDim.x + threadIdx.x;
  if (e >= E) return;
  int s, d;
  if (flags[0]) { s = ei[2 * e]; d = ei[2 * (E + e)]; }
  else          { s = ei[e];     d = ei[E + e]; }
  s = ((unsigned)s < (unsigned)N) ? s : 0;
  d = ((unsigned)d < (unsigned)N) ? d : 0;
  int pos = atomicAdd(&cur[d], 1);
  edgeSD[pos] = make_int2(s, d);   // one 8B store: 1 cache line touched
}

// -- layer-1 convert+norm: fp32/bf16 x -> f16 rows + int8 rows + invq --------

__global__ __launch_bounds__(256) void convert_norm_kernel(
    const float* __restrict__ xf, const unsigned short* __restrict__ xb,
    const int* __restrict__ flags, _Float16* __restrict__ xo,
    unsigned char* __restrict__ xq, float* __restrict__ invq, int n) {
  int row = blockIdx.x * 4 + (threadIdx.x >> 6);
  int lane = threadIdx.x & 63;
  if (row >= n) return;
  float ss = 0.f, mx = 0.f;
  float vals[8];
  H8 o;
  if (flags[1]) {
    const float4* vp = reinterpret_cast<const float4*>(xf + (size_t)row * 512) + lane * 2;
    float4 a = vp[0], b = vp[1];
    vals[0] = a.x; vals[1] = a.y; vals[2] = a.z; vals[3] = a.w;
    vals[4] = b.x; vals[5] = b.y; vals[6] = b.z; vals[7] = b.w;
  } else {
    uint4 v = *(reinterpret_cast<const uint4*>(xb + (size_t)row * 512) + lane);
    unsigned int a[4] = {v.x, v.y, v.z, v.w};
    #pragma unroll
    for (int i = 0; i < 4; i++) {
      vals[2 * i] = bf2f(a[i] & 0xffffu);
      vals[2 * i + 1] = bf2f(a[i] >> 16);
    }
  }
  #pragma unroll
  for (int i = 0; i < 8; i++) {
    ss += vals[i] * vals[i];
    mx = fmaxf(mx, fabsf(vals[i]));
    o.v[i] = (_Float16)vals[i];
  }
  *(reinterpret_cast<uint4*>(xo + (size_t)row * 512) + lane) = o.u;
  ss = wave_sum(ss);
  mx = wave_max(mx);
  float scale = (mx > 0.f) ? 127.0f / mx : 0.f;
  uint2 qo;
  unsigned int q0 = 0, q1 = 0;
  #pragma unroll
  for (int i = 0; i < 4; i++) {
    int q = (int)rintf(vals[i] * scale);
    q0 |= ((unsigned int)(q & 0xff)) << (8 * i);
  }
  #pragma unroll
  for (int i = 0; i < 4; i++) {
    int q = (int)rintf(vals[4 + i] * scale);
    q1 |= ((unsigned int)(q & 0xff)) << (8 * i);
  }
  qo.x = q0; qo.y = q1;
  *(reinterpret_cast<uint2*>(xq + (size_t)row * 512) + lane) = qo;
  if (lane == 0)
    invq[row] = (mx > 0.f && ss > 0.f) ? (mx / 127.0f) * rsqrtf(ss) : 0.f;
}

// fallback norm over raw x
__global__ __launch_bounds__(256) void norm8_kernel(const unsigned short* __restrict__ hb,
                                                    const float* __restrict__ hf,
                                                    const int* __restrict__ flags,
                                                    float* __restrict__ invn, int n) {
  int wid = blockIdx.x * 4 + (threadIdx.x >> 6);
  int lane = threadIdx.x & 63;
  if (wid >= n) return;
  float s = 0.f;
  if (flags[1]) {
    const float4* vp = reinterpret_cast<const float4*>(hf + (size_t)wid * 512) + lane * 2;
    float4 a = vp[0], b = vp[1];
    s = a.x*a.x + a.y*a.y + a.z*a.z + a.w*a.w + b.x*b.x + b.y*b.y + b.z*b.z + b.w*b.w;
  } else {
    uint4 v = *(reinterpret_cast<const uint4*>(hb + (size_t)wid * 512) + lane);
    unsigned int a[4] = {v.x, v.y, v.z, v.w};
    #pragma unroll
    for (int i = 0; i < 4; i++) {
      float lo = bf2f(a[i] & 0xffffu), hi = bf2f(a[i] >> 16);
      s += lo * lo + hi * hi;
    }
  }
  s = wave_sum(s);
  if (lane == 0) invn[wid] = (s == 0.f) ? 1.0f : rsqrtf(s);
}

// --- int8 cosine sim: 16-lane groups, 8 edges/wave, sdot4, packed atomic ---

template<int RB>
__global__ __launch_bounds__(256) void simq2_kernel(const unsigned char* __restrict__ q,
                                                    const int2* __restrict__ edgeSD,
                                                    const float* __restrict__ invq,
                                                    float* __restrict__ w,
                                                    double* __restrict__ packed,
                                                    int E, int chunk) {
  int nb = (blockIdx.x & 7) * chunk + (blockIdx.x >> 3);
  int lane = threadIdx.x & 63;
  int l = lane & 15, g = lane >> 4;
  int j0 = (nb * 4 + (threadIdx.x >> 6)) * 8;
  if (j0 >= E) return;
  int sj[2], tj[2];
  bool val[2];
  #pragma unroll
  for (int b = 0; b < 2; b++) {
    int j = j0 + b * 4 + g;
    val[b] = j < E;
    int2 e = edgeSD[val[b] ? j : 0];
    sj[b] = e.x;
    tj[b] = e.y;
  }
  int acc[2];
  if constexpr (RB == 512) {
    uint4 sa[2][2], ta[2][2];
    #pragma unroll
    for (int b = 0; b < 2; b++) {
      const unsigned char* sp = q + (size_t)sj[b] * 512 + l * 16;
      const unsigned char* tp = q + (size_t)tj[b] * 512 + l * 16;
      sa[b][0] = *reinterpret_cast<const uint4*>(sp);
      sa[b][1] = *reinterpret_cast<const uint4*>(sp + 256);
      ta[b][0] = *reinterpret_cast<const uint4*>(tp);
      ta[b][1] = *reinterpret_cast<const uint4*>(tp + 256);
    }
    #pragma unroll
    for (int b = 0; b < 2; b++) {
      int a = 0;
      a = dot4i((int)sa[b][0].x, (int)ta[b][0].x, a);
      a = dot4i((int)sa[b][0].y, (int)ta[b][0].y, a);
      a = dot4i((int)sa[b][0].z, (int)ta[b][0].z, a);
      a = dot4i((int)sa[b][0].w, (int)ta[b][0].w, a);
      a = dot4i((int)sa[b][1].x, (int)ta[b][1].x, a);
      a = dot4i((int)sa[b][1].y, (int)ta[b][1].y, a);
      a = dot4i((int)sa[b][1].z, (int)ta[b][1].z, a);
      a = dot4i((int)sa[b][1].w, (int)ta[b][1].w, a);
      acc[b] = a;
    }
  } else if constexpr (RB == 256) {
    uint4 sa[2], ta[2];
    #pragma unroll
    for (int b = 0; b < 2; b++) {
      sa[b] = *reinterpret_cast<const uint4*>(q + (size_t)sj[b] * 256 + l * 16);
      ta[b] = *reinterpret_cast<const uint4*>(q + (size_t)tj[b] * 256 + l * 16);
    }
    #pragma unroll
    for (int b = 0; b < 2; b++) {
      int a = 0;
      a = dot4i((int)sa[b].x, (int)ta[b].x, a);
      a = dot4i((int)sa[b].y, (int)ta[b].y, a);
      a = dot4i((int)sa[b].z, (int)ta[b].z, a);
      a = dot4i((int)sa[b].w, (int)ta[b].w, a);
      acc[b] = a;
    }
  } else {  // RB == 64
    unsigned int sa[2], ta[2];
    #pragma unroll
    for (int b = 0; b < 2; b++) {
      sa[b] = *reinterpret_cast<const unsigned int*>(q + (size_t)sj[b] * 64 + l * 4);
      ta[b] = *reinterpret_cast<const unsigned int*>(q + (size_t)tj[b] * 64 + l * 4);
    }
    #pragma unroll
    for (int b = 0; b < 2; b++) acc[b] = dot4i((int)sa[b], (int)ta[b], 0);
  }
  #pragma unroll
  for (int m = 1; m < 16; m <<= 1) {
    acc[0] += __shfl_xor(acc[0], m, 64);
    acc[1] += __shfl_xor(acc[1], m, 64);
  }
  if (l == 0) {
    #pragma unroll
    for (int b = 0; b < 2; b++) {
      if (val[b]) {
        int j = j0 + b * 4 + g;
        float simv = (float)acc[b] * invq[sj[b]] * invq[tj[b]];
        float wv = (sj[b] != tj[b] && simv > 0.f) ? simv : 0.f;
        w[j] = wv;
        if (wv > 0.f)
          atomicAdd(&packed[sj[b]], (double)wv + CNT_SCALE);  // one atomic: count+sum
      }
    }
  }
}

// fallback layer-1 sim on raw x (packed atomic)
__global__ __launch_bounds__(256) void simf_kernel(const unsigned short* __restrict__ hb,
                                                   const float* __restrict__ hf,
                                                   const int* __restrict__ flags,
                                                   const int2* __restrict__ edgeSD,
                                                   const float* __restrict__ invn,
                                                   float* __restrict__ w,
                                                   double* __restrict__ packed, int E) {
  int j = blockIdx.x * 4 + (threadIdx.x >> 6);
  int lane = threadIdx.x & 63;
  if (j >= E) return;
  int2 e = edgeSD[j];
  int s = e.x, t = e.y;
  float acc = 0.f;
  if (flags[1]) {
    const float4* ap = reinterpret_cast<const float4*>(hf + (size_t)s * 512) + lane * 2;
    const float4* bp = reinterpret_cast<const float4*>(hf + (size_t)t * 512) + lane * 2;
    float4 a0 = ap[0], a1 = ap[1], b0 = bp[0], b1 = bp[1];
    acc = a0.x*b0.x + a0.y*b0.y + a0.z*b0.z + a0.w*b0.w
        + a1.x*b1.x + a1.y*b1.y + a1.z*b1.z + a1.w*b1.w;
  } else {
    uint4 a = *(reinterpret_cast<const uint4*>(hb + (size_t)s * 512) + lane);
    uint4 b = *(reinterpret_cast<const uint4*>(hb + (size_t)t * 512) + lane);
    unsigned int av[4] = {a.x, a.y, a.z, a.w};
    unsigned int bv[4] = {b.x, b.y, b.z, b.w};
    #pragma unroll
    for (int i = 0; i < 4; i++)
      acc += bf2f(av[i] & 0xffffu) * bf2f(bv[i] & 0xffffu)
           + bf2f(av[i] >> 16) * bf2f(bv[i] >> 16);
  }
  acc = wave_sum(acc);
  if (lane == 0) {
    float simv = acc * invn[s] * invn[t];
    float wv = (s != t && simv > 0.f) ? simv : 0.f;
    w[j] = wv;
    if (wv > 0.f) atomicAdd(&packed[s], (double)wv + CNT_SCALE);
  }
}

// ------ unpack packed double -> rowsum/degcnt ------

__global__ void unpack_kernel(const double* __restrict__ packed,
                              float* __restrict__ rowsum, float* __restrict__ degcnt,
                              int n) {
  int i = blockIdx.x * blockDim.x + threadIdx.x;
  if (i >= n) return;
  double v = packed[i];
  double c = floor(v * (1.0 / CNT_SCALE));
  rowsum[i] = (float)(v - c * CNT_SCALE);
  degcnt[i] = (float)c;
}

// ------ fused deg pass (dst-CSR, wave-per-node) ------

__global__ __launch_bounds__(256) void deg_kernel(
    float* __restrict__ w, const int2* __restrict__ edgeSD, const int* __restrict__ off,
    const float* __restrict__ rowsum, const float* __restrict__ degcnt,
    float* __restrict__ sw, float* __restrict__ dinv, int n) {
  int i = blockIdx.x * 4 + (threadIdx.x >> 6);
  if (i >= n) return;
  int lane = threadIdx.x & 63;
  int e0 = off[i], e1 = off[i + 1];
  float sum = 0.f;
  for (int j = e0 + lane; j < e1; j += 64) {
    float wv = w[j];
    if (wv > 0.f) {
      float ew = expf(wv / rowsum[edgeSD[j].x]);
      w[j] = ew;
      sum += ew;
    }
  }
  sum = wave_sum(sum);
  float swi = expf(1.0f / (degcnt[i] + 1.0f));
  if (lane == 0) {
    sw[i] = swi;
    dinv[i] = rsqrtf(swi + sum);
  }
}

// ---------------- GEMM (f16 MFMA) ----------------

__global__ void transpose_kernel(const unsigned short* __restrict__ Wb,
                                 const float* __restrict__ Wf,
                                 const int* __restrict__ flags,
                                 _Float16* __restrict__ WT,
                                 int K, int Nc, int Npad) {
  int idx = blockIdx.x * blockDim.x + threadIdx.x;
  if (idx >= Npad * K) return;
  int nn = idx / K, k = idx - nn * K;
  _Float16 v = (_Float16)0.f;
  if (nn < Nc) {
    if (flags[1]) v = (_Float16)Wf[(size_t)k * Nc + nn];
    else          v = (_Float16)bf2f((unsigned int)Wb[(size_t)k * Nc + nn]);
  }
  WT[idx] = v;
}

__global__ void transpose1_kernel(const unsigned short* __restrict__ Wb,
                                  const float* __restrict__ Wf,
                                  const int* __restrict__ flags,
                                  _Float16* __restrict__ WTb) {
  int idx = blockIdx.x * blockDim.x + threadIdx.x;
  if (idx >= 512 * 256) return;
  int kk = idx >> 13;
  int rem = idx & 8191;
  int nn = rem >> 5;
  int kidx = rem & 31;
  int k = kk * 32 + kidx;
  _Float16 v;
  if (flags[1]) v = (_Float16)Wf[k * 256 + nn];
  else          v = (_Float16)bf2f((unsigned int)Wb[k * 256 + nn]);
  WTb[idx] = v;
}

__global__ __launch_bounds__(256) void gemm1_lds_kernel(
    const _Float16* __restrict__ Ah, const float* __restrict__ Af,
    const unsigned short* __restrict__ Abf, const int* __restrict__ flags,
    int useflags, const _Float16* __restrict__ BTb, _Float16* __restrict__ C,
    int M) {
  constexpr int NT = 16, KSTEPS = 16, K = 512, LS = 40;
  __shared__ _Float16 bs[256 * LS];
  int t = threadIdx.x;
  int wid = t >> 6, lane = t & 63;
  int mt = blockIdx.x * 4 + wid;
  bool act = (mt * 16 < M);
  int r = lane & 15, quad = lane >> 4;
  int m0 = mt * 16;
  int mode = useflags ? (flags[1] ? 1 : 2) : 0;
  floatx4 acc[NT];
  #pragma unroll
  for (int nt = 0; nt < NT; nt++) acc[nt] = floatx4{0.f, 0.f, 0.f, 0.f};
  int arow = act ? (m0 + r) : 0;
  const uint4* ap = reinterpret_cast<const uint4*>(Ah + (size_t)arow * K);
  const float* af = Af + (size_t)arow * K + quad * 8;
  const unsigned short* ab = Abf + (size_t)arow * K + quad * 8;
  for (int kk = 0; kk < KSTEPS; kk++) {
    __syncthreads();
    {
      const uint4* bsrc = reinterpret_cast<const uint4*>(BTb + kk * 8192) + t * 4;
      uint4 b0 = bsrc[0], b1 = bsrc[1], b2 = bsrc[2], b3 = bsrc[3];
      uint4* bdst = reinterpret_cast<uint4*>(bs + t * LS);
      bdst[0] = b0; bdst[1] = b1; bdst[2] = b2; bdst[3] = b3;
    }
    __syncthreads();
    if (act) {
      H8 a;
      if (mode == 1) {
        float4 x0 = *reinterpret_cast<const float4*>(af + kk * 32);
        float4 x1 = *reinterpret_cast<const float4*>(af + kk * 32 + 4);
        a.v[0] = (_Float16)x0.x; a.v[1] = (_Float16)x0.y;
        a.v[2] = (_Float16)x0.z; a.v[3] = (_Float16)x0.w;
        a.v[4] = (_Float16)x1.x; a.v[5] = (_Float16)x1.y;
        a.v[6] = (_Float16)x1.z; a.v[7] = (_Float16)x1.w;
      } else if (mode == 2) {
        uint4 u = *reinterpret_cast<const uint4*>(ab + kk * 32);
        unsigned int uu[4] = {u.x, u.y, u.z, u.w};
        #pragma unroll
        for (int i = 0; i < 4; i++) {
          a.v[2 * i] = (_Float16)bf2f(uu[i] & 0xffffu);
          a.v[2 * i + 1] = (_Float16)bf2f(uu[i] >> 16);
        }
      } else {
        a.u = ap[(kk << 2) + quad];
      }
      #pragma unroll
      for (int nt = 0; nt < NT; nt++) {
        H8 b;
        b.u = *reinterpret_cast<const uint4*>(bs + (nt * 16 + r) * LS + quad * 8);
        acc[nt] = __builtin_amdgcn_mfma_f32_16x16x32_f16(a.v, b.v, acc[nt], 0, 0, 0);
      }
    }
  }
  if (act) {
    #pragma unroll
    for (int nt = 0; nt < NT; nt++) {
      #pragma unroll
      for (int i = 0; i < 4; i++)
        C[(size_t)(m0 + quad * 4 + i) * 256 + nt * 16 + r] = (_Float16)acc[nt][i];
    }
  }
}

template<int NT, int KSTEPS>
__global__ __launch_bounds__(256) void gemmw_kernel(const _Float16* __restrict__ Ah,
                                                    const _Float16* __restrict__ BT,
                                                    _Float16* __restrict__ C,
                                                    int M, int Npad) {
  constexpr int K = KSTEPS * 32;
  int mt = blockIdx.x * 4 + (threadIdx.x >> 6);
  if (mt * 16 >= M) return;
  int lane = threadIdx.x & 63;
  int r = lane & 15, quad = lane >> 4;
  int m0 = mt * 16;
  floatx4 acc[NT];
  #pragma unroll
  for (int nt = 0; nt < NT; nt++) acc[nt] = floatx4{0.f, 0.f, 0.f, 0.f};
  const uint4* ap = reinterpret_cast<const uint4*>(Ah + (size_t)(m0 + r) * K);
  for (int kk = 0; kk < KSTEPS; kk++) {
    H8 a;
    a.u = ap[(kk << 2) + quad];
    #pragma unroll
    for (int nt = 0; nt < NT; nt++) {
      H8 b;
      b.u = *reinterpret_cast<const uint4*>(BT + (size_t)(nt * 16 + r) * K + kk * 32 + quad * 8);
      acc[nt] = __builtin_amdgcn_mfma_f32_16x16x32_f16(a.v, b.v, acc[nt], 0, 0, 0);
    }
  }
  #pragma unroll
  for (int nt = 0; nt < NT; nt++) {
    #pragma unroll
    for (int i = 0; i < 4; i++)
      C[(size_t)(m0 + quad * 4 + i) * Npad + nt * 16 + r] = (_Float16)acc[nt][i];
  }
}

// ------- aggregation: wave-per-node, scalar broadcast, no LDS/barriers -------

template<int NC, int STRIDE, int VEC, bool DOQ>
__global__ __launch_bounds__(256) void aggw_relu_kernel(
    const _Float16* __restrict__ hp, const float* __restrict__ ew,
    const int2* __restrict__ edgeSD, const int* __restrict__ off,
    const float* __restrict__ dinv, const float* __restrict__ sw,
    const unsigned short* __restrict__ biasb, const float* __restrict__ biasf,
    const int* __restrict__ flags, _Float16* __restrict__ out,
    unsigned char* __restrict__ qout, float* __restrict__ invn, int n) {
  constexpr int ACT = NC / VEC;
  int i = blockIdx.x * 4 + (threadIdx.x >> 6);
  if (i >= n) return;
  int lane = threadIdx.x & 63;
  float di = dinv[i];
  float sii = sw[i] * di * di;
  float acc[VEC];
  #pragma unroll
  for (int v = 0; v < VEC; v++) acc[v] = 0.f;
  if (lane < ACT) {
    if constexpr (VEC == 4) {
      H4 hv;
      hv.u = *reinterpret_cast<const uint2*>(hp + (size_t)i * STRIDE + lane * 4);
      #pragma unroll
      for (int v = 0; v < 4; v++) acc[v] = sii * (float)hv.e[v];
    } else {
      acc[0] = sii * (float)hp[(size_t)i * STRIDE + lane];
    }
  }
  int e0 = off[i], e1 = off[i + 1];
  for (int base = e0; base < e1; base += 64) {
    int j = base + lane;
    int sreg = 0;
    float creg = 0.f;
    if (j < e1) {
      sreg = edgeSD[j].x;
      float e = ew[j];
      if (e != 0.f) creg = e * dinv[sreg] * di;
    }
    int m = min(64, e1 - base);
    for (int k = 0; k < m; k++) {
      float cfk = rlf(creg, k);
      if (cfk != 0.f) {
        int sk = rl(sreg, k);
        if (lane < ACT) {
          if constexpr (VEC == 4) {
            H4 hv;
            hv.u = *reinterpret_cast<const uint2*>(hp + (size_t)sk * STRIDE + lane * 4);
            #pragma unroll
            for (int v = 0; v < 4; v++) acc[v] += cfk * (float)hv.e[v];
          } else {
            acc[0] += cfk * (float)hp[(size_t)sk * STRIDE + lane];
          }
        }
      }
    }
  }
  float nrm = 0.f, lmax = 0.f;
  float xv[VEC];
  if (lane < ACT) {
    if constexpr (VEC == 4) {
      H4 ov;
      #pragma unroll
      for (int v = 0; v < 4; v++) {
        int c = lane * 4 + v;
        float bb = flags[1] ? biasf[c] : bf2f((unsigned int)biasb[c]);
        float x = acc[v] + bb;
        x = x > 0.f ? x : 0.f;
        xv[v] = x;
        ov.e[v] = (_Float16)x;
        nrm += x * x;
        lmax = fmaxf(lmax, x);
      }
      *reinterpret_cast<uint2*>(out + (size_t)i * NC + lane * 4) = ov.u;
    } else {
      float bb = flags[1] ? biasf[lane] : bf2f((unsigned int)biasb[lane]);
      float x = acc[0] + bb;
      x = x > 0.f ? x : 0.f;
      xv[0] = x;
      out[(size_t)i * NC + lane] = (_Float16)x;
      nrm = x * x;
      lmax = x;
    }
  }
  nrm = wave_sum(nrm);
  if constexpr (DOQ) {
    float mx = wave_max(lmax);
    float scale = (mx > 0.f) ? 127.0f / mx : 0.f;
    if (lane < ACT) {
      if constexpr (VEC == 4) {
        unsigned int qw = 0;
        #pragma unroll
        for (int v = 0; v < 4; v++) {
          int qq = (int)(xv[v] * scale + 0.5f);
          qw |= ((unsigned int)(qq & 0xff)) << (8 * v);
        }
        *reinterpret_cast<unsigned int*>(qout + (size_t)i * NC + lane * 4) = qw;
      } else {
        qout[(size_t)i * NC + lane] = (unsigned char)(int)(xv[0] * scale + 0.5f);
      }
    }
    if (lane == 0)
      invn[i] = (mx > 0.f && nrm > 0.f) ? (mx / 127.0f) * rsqrtf(nrm) : 0.f;
  } else {
    if (lane == 0) invn[i] = (nrm == 0.f) ? 1.0f : rsqrtf(nrm);
  }
}

__global__ __launch_bounds__(256) void aggw_lsm_kernel(
    const _Float16* __restrict__ hp, const float* __restrict__ ew,
    const int2* __restrict__ edgeSD, const int* __restrict__ off,
    const float* __restrict__ dinv, const float* __restrict__ sw,
    const unsigned short* __restrict__ biasb, const float* __restrict__ biasf,
    const int* __restrict__ flags, void* __restrict__ outv, int n) {
  constexpr int NC = 40, STRIDE = 48;
  int i = blockIdx.x * 4 + (threadIdx.x >> 6);
  if (i >= n) return;
  int lane = threadIdx.x & 63;
  float di = dinv[i];
  float acc = 0.f;
  if (lane < NC) acc = sw[i] * di * di * (float)hp[(size_t)i * STRIDE + lane];
  int e0 = off[i], e1 = off[i + 1];
  for (int base = e0; base < e1; base += 64) {
    int j = base + lane;
    int sreg = 0;
    float creg = 0.f;
    if (j < e1) {
      sreg = edgeSD[j].x;
      float e = ew[j];
      if (e != 0.f) creg = e * dinv[sreg] * di;
    }
    int m = min(64, e1 - base);
    for (int k = 0; k < m; k++) {
      float cfk = rlf(creg, k);
      if (cfk != 0.f) {
        int sk = rl(sreg, k);
        if (lane < NC) acc += cfk * (float)hp[(size_t)sk * STRIDE + lane];
      }
    }
  }
  int f32 = flags[1];
  float bb = 0.f;
  if (lane < NC) bb = f32 ? biasf[lane] : bf2f((unsigned int)biasb[lane]);
  float v = (lane < NC) ? acc + bb : -3.0e38f;
  float vm = wave_max(v);
  float ex = (lane < NC) ? expf(v - vm) : 0.f;
  float se = wave_sum(ex);
  float ls = logf(se);
  if (lane < NC) {
    float r = v - vm - ls;
    if (f32) ((float*)outv)[(size_t)i * NC + lane] = r;
    else ((unsigned short*)outv)[(size_t)i * NC + lane] = f2bf(r);
  }
}

// ---------------- host ----------------

extern "C" void kernel_launch(void* const* d_in, const int* in_sizes, int n_in,
                              void* d_out, int out_size, void* d_ws, size_t ws_size,
                              hipStream_t stream) {
  const unsigned short* xb = (const unsigned short*)d_in[0];
  const float* xf          = (const float*)d_in[0];
  const int* ei            = (const int*)d_in[1];

  const int H  = in_sizes[3];            // 256
  const int F  = in_sizes[2] / H;        // 512
  const int D2 = in_sizes[5];            // 64
  const int C  = in_sizes[7];            // 40
  const int N  = in_sizes[0] / F;        // 50000
  const int E  = in_sizes[1] / 2;        // 1600000
  const int CP = 48;

  char* p = (char*)d_ws;
  auto alloc = [&](size_t bytes) -> char* {
    char* r = p;
    p += (bytes + 255) & ~(size_t)255;
    return r;
  };
  int2*  edgeSD = (int2*)alloc((size_t)E * 8 + 64);
  float* wbuf   = (float*)alloc((size_t)E * 4);
  int*   off    = (int*)alloc((size_t)(N + 1) * 4);
  int*   cur    = (int*)alloc((size_t)N * 4);
  float* invn   = (float*)alloc((size_t)N * 4);
  float* rowsum = (float*)alloc((size_t)N * 4);
  float* degcnt = (float*)alloc((size_t)N * 4);
  float* sw     = (float*)alloc((size_t)N * 4);
  float* dinv   = (float*)alloc((size_t)N * 4);
  double* packed = (double*)alloc((size_t)N * 8);
  int*   flags  = (int*)alloc(256);
  int*   bsum   = (int*)alloc(4096 * 4);
  _Float16* WT  = (_Float16*)alloc((size_t)256 * 512 * 2);
  _Float16* hp  = (_Float16*)alloc((size_t)N * 256 * 2);
  size_t used = (size_t)(p - (char*)d_ws);
  size_t xh_bytes = (size_t)N * 512 * 2;
  bool big = (used + xh_bytes + 256) <= ws_size;
  _Float16* xh = big ? (_Float16*)alloc(xh_bytes) : hp;

  unsigned char* xq = (unsigned char*)hp;                         // N*512 B
  _Float16* h1 = (_Float16*)d_in[0];                              // N*512 B (f16)
  unsigned char* h1q = (unsigned char*)d_in[0] + (size_t)N * 512; // N*256 B
  unsigned char* h2q = (unsigned char*)d_in[0] + (size_t)N * 768; // N*64 B
  _Float16* h2 = hp + (size_t)N * 64;

  const int TB = 256;
  int nblk = (N + TB - 1) / TB;
  int eblk = (E + TB - 1) / TB;
  int nwav = (N + 3) / 4;
  int ewav = (E + 3) / 4;
  int mt4  = (N / 16 + 3) / 4;
  int nb1024 = (N + 1023) / 1024;
  int sblocks8 = (E + 31) / 32;
  int schunk8 = (sblocks8 + 7) / 8;
  int sgrid8 = schunk8 * 8;

  detect_kernel<<<1, 256, 0, stream>>>(ei, (const unsigned int*)d_in[2], flags, E);

  // dst-CSR with packed (src,dst)
  hipMemsetAsync(cur, 0, (size_t)N * 4, stream);
  count_kernel<<<eblk, TB, 0, stream>>>(ei, flags, cur, E, N);
  scan1_kernel<<<nb1024, 1024, 0, stream>>>(cur, off, bsum, N);
  scan2_kernel<<<1, 1024, 0, stream>>>(bsum, nb1024);
  scan3_kernel<<<nblk, TB, 0, stream>>>(off, cur, bsum, N);
  fill_kernel<<<eblk, TB, 0, stream>>>(ei, flags, cur, edgeSD, E, N);

  // ---------- layer 1: x(512) -> h1(256) ----------
  hipMemsetAsync(packed, 0, (size_t)N * 8, stream);
  if (big) {
    convert_norm_kernel<<<nwav, TB, 0, stream>>>(xf, xb, flags, xh, xq, invn, N);
    simq2_kernel<512><<<sgrid8, TB, 0, stream>>>(xq, edgeSD, invn, wbuf, packed, E, schunk8);
  } else {
    norm8_kernel<<<nwav, TB, 0, stream>>>(xb, xf, flags, invn, N);
    simf_kernel<<<ewav, TB, 0, stream>>>(xb, xf, flags, edgeSD, invn, wbuf, packed, E);
  }
  unpack_kernel<<<nblk, TB, 0, stream>>>(packed, rowsum, degcnt, N);
  deg_kernel<<<nwav, TB, 0, stream>>>(wbuf, edgeSD, off, rowsum, degcnt, sw, dinv, N);
  transpose1_kernel<<<(512 * 256 + TB - 1) / TB, TB, 0, stream>>>(
      (const unsigned short*)d_in[2], (const float*)d_in[2], flags, WT);
  gemm1_lds_kernel<<<mt4, TB, 0, stream>>>(
      xh, xf, xb, flags, big ? 0 : 1, WT, hp, N);
  aggw_relu_kernel<256, 256, 4, true><<<nwav, TB, 0, stream>>>(
      hp, wbuf, edgeSD, off, dinv, sw,
      (const unsigned short*)d_in[3], (const float*)d_in[3], flags, h1, h1q, invn, N);

  // ---------- layer 2: h1(256) -> h2(64) ----------
  hipMemsetAsync(packed, 0, (size_t)N * 8, stream);
  simq2_kernel<256><<<sgrid8, TB, 0, stream>>>(h1q, edgeSD, invn, wbuf, packed, E, schunk8);
  unpack_kernel<<<nblk, TB, 0, stream>>>(packed, rowsum, degcnt, N);
  deg_kernel<<<nwav, TB, 0, stream>>>(wbuf, edgeSD, off, rowsum, degcnt, sw, dinv, N);
  transpose_kernel<<<(D2 * H + TB - 1) / TB, TB, 0, stream>>>(
      (const unsigned short*)d_in[4], (const float*)d_in[4], flags, WT, H, D2, D2);
  gemmw_kernel<4, 8><<<mt4, TB, 0, stream>>>(h1, WT, hp, N, D2);
  aggw_relu_kernel<64, 64, 1, true><<<nwav, TB, 0, stream>>>(
      hp, wbuf, edgeSD, off, dinv, sw,
      (const unsigned short*)d_in[5], (const float*)d_in[5], flags, h2, h2q, invn, N);

  // ---------- layer 3: h2(64) -> out(40), fused log_softmax ----------
  hipMemsetAsync(packed, 0, (size_t)N * 8, stream);
  simq2_kernel<64><<<sgrid8, TB, 0, stream>>>(h2q, edgeSD, invn, wbuf, packed, E, schunk8);
  unpack_kernel<<<nblk, TB, 0, stream>>>(packed, rowsum, degcnt, N);
  deg_kernel<<<nwav, TB, 0, stream>>>(wbuf, edgeSD, off, rowsum, degcnt, sw, dinv, N);
  transpose_kernel<<<(CP * D2 + TB - 1) / TB, TB, 0, stream>>>(
      (const unsigned short*)d_in[6], (const float*)d_in[6], flags, WT, D2, C, CP);
  gemmw_kernel<3, 2><<<mt4, TB, 0, stream>>>(h2, WT, hp, N, CP);
  aggw_lsm_kernel<<<nwav, TB, 0, stream>>>(
      hp, wbuf, edgeSD, off, dinv, sw,
      (const unsigned short*)d_in[7], (const float*)d_in[7], flags, d_out, N);
}